// Round 4
// baseline (568.371 us; speedup 1.0000x reference)
//
#include <hip/hip_runtime.h>

#define DI __device__ __forceinline__

DI float fsig(float v)  { return 1.0f / (1.0f + __expf(-v)); }
DI float ftanh(float v) { return 1.0f - 2.0f / (__expf(2.0f * v) + 1.0f); }

// ===================== LSTM scan, 4-way K-split =====================
// 512 threads: r0 = tid&127 (hidden unit), kq = tid>>7 (K-quarter of [x(32)|h(128)]).
// Thread computes partials for all 4 gates of unit r0 over its 40-float K-quarter.
// Weights: 4 gates x 10 float4 = 160 VGPRs. MODE 0: record pre-step (h|c). MODE 1: write h.
template <int MODE>
DI void lstm_scan2(const float* __restrict__ xin,  // [128][32]
                   const float* __restrict__ Wih,  // [512][32]
                   const float* __restrict__ Whh,  // [512][128]
                   const float* __restrict__ bih,
                   const float* __restrict__ bhh,
                   float* __restrict__ rec,        // MODE 0: [128][256]
                   float* __restrict__ outp,       // MODE 1: stride 256
                   float* lds)
{
    const int tid = threadIdx.x;
    const int r0 = tid & 127;
    const int kq = tid >> 7;
    float* xl = lds;          // 4096
    float* hl = lds + 4096;   // 128
    float* pl = lds + 4224;   // 2048 : pl[kq*512 + g*128 + r0]

    for (int i = tid; i < 4096; i += 512) xl[i] = xin[i];
    if (tid < 128) hl[tid] = 0.f;

    // K-quarter kq covers virtual K index [40kq, 40kq+40):
    //  kq0: Wih[r][0..32) + Whh[r][0..8);  kq>=1: Whh[r][40kq-32 .. 40kq+8)
    float4 wq[4][10];
    if (kq == 0) {
        #pragma unroll
        for (int g = 0; g < 4; ++g) {
            const int r = g * 128 + r0;
            const float4* pi4 = (const float4*)(Wih + r * 32);
            #pragma unroll
            for (int i = 0; i < 8; ++i) wq[g][i] = pi4[i];
            const float4* ph4 = (const float4*)(Whh + r * 128);
            wq[g][8] = ph4[0]; wq[g][9] = ph4[1];
        }
    } else {
        const int off = 40 * kq - 32;  // 8, 48, 88
        #pragma unroll
        for (int g = 0; g < 4; ++g) {
            const int r = g * 128 + r0;
            const float4* ph4 = (const float4*)(Whh + r * 128 + off);
            #pragma unroll
            for (int j = 0; j < 10; ++j) wq[g][j] = ph4[j];
        }
    }
    float b0 = 0.f, b1 = 0.f, b2 = 0.f, b3 = 0.f, hreg = 0.f, creg = 0.f;
    if (tid < 128) {
        b0 = bih[tid]       + bhh[tid];
        b1 = bih[128 + tid] + bhh[128 + tid];
        b2 = bih[256 + tid] + bhh[256 + tid];
        b3 = bih[384 + tid] + bhh[384 + tid];
    }
    __syncthreads();

    for (int t = 0; t < 128; ++t) {
        float a0 = 0.f, a1 = 0.f, a2 = 0.f, a3 = 0.f;
        if (kq == 0) {
            const float4* x4 = (const float4*)(xl + t * 32);
            #pragma unroll
            for (int i = 0; i < 8; ++i) {
                float4 v = x4[i];
                a0 += wq[0][i].x * v.x + wq[0][i].y * v.y + wq[0][i].z * v.z + wq[0][i].w * v.w;
                a1 += wq[1][i].x * v.x + wq[1][i].y * v.y + wq[1][i].z * v.z + wq[1][i].w * v.w;
                a2 += wq[2][i].x * v.x + wq[2][i].y * v.y + wq[2][i].z * v.z + wq[2][i].w * v.w;
                a3 += wq[3][i].x * v.x + wq[3][i].y * v.y + wq[3][i].z * v.z + wq[3][i].w * v.w;
            }
            const float4* h4 = (const float4*)hl;
            #pragma unroll
            for (int j = 0; j < 2; ++j) {
                float4 v = h4[j];
                a0 += wq[0][8+j].x * v.x + wq[0][8+j].y * v.y + wq[0][8+j].z * v.z + wq[0][8+j].w * v.w;
                a1 += wq[1][8+j].x * v.x + wq[1][8+j].y * v.y + wq[1][8+j].z * v.z + wq[1][8+j].w * v.w;
                a2 += wq[2][8+j].x * v.x + wq[2][8+j].y * v.y + wq[2][8+j].z * v.z + wq[2][8+j].w * v.w;
                a3 += wq[3][8+j].x * v.x + wq[3][8+j].y * v.y + wq[3][8+j].z * v.z + wq[3][8+j].w * v.w;
            }
        } else {
            const float4* h4 = (const float4*)(hl + 40 * kq - 32);
            #pragma unroll
            for (int j = 0; j < 10; ++j) {
                float4 v = h4[j];
                a0 += wq[0][j].x * v.x + wq[0][j].y * v.y + wq[0][j].z * v.z + wq[0][j].w * v.w;
                a1 += wq[1][j].x * v.x + wq[1][j].y * v.y + wq[1][j].z * v.z + wq[1][j].w * v.w;
                a2 += wq[2][j].x * v.x + wq[2][j].y * v.y + wq[2][j].z * v.z + wq[2][j].w * v.w;
                a3 += wq[3][j].x * v.x + wq[3][j].y * v.y + wq[3][j].z * v.z + wq[3][j].w * v.w;
            }
        }
        pl[kq * 512 +       r0] = a0;
        pl[kq * 512 + 128 + r0] = a1;
        pl[kq * 512 + 256 + r0] = a2;
        pl[kq * 512 + 384 + r0] = a3;
        __syncthreads();
        if (tid < 128) {
            float pi = b0 + pl[tid]        + pl[512 + tid]  + pl[1024 + tid] + pl[1536 + tid];
            float pf = b1 + pl[128 + tid]  + pl[640 + tid]  + pl[1152 + tid] + pl[1664 + tid];
            float pg = b2 + pl[256 + tid]  + pl[768 + tid]  + pl[1280 + tid] + pl[1792 + tid];
            float po = b3 + pl[384 + tid]  + pl[896 + tid]  + pl[1408 + tid] + pl[1920 + tid];
            if (MODE == 0) {
                rec[t * 256 + tid]       = hreg;   // pre-step state
                rec[t * 256 + 128 + tid] = creg;
            }
            float iv = fsig(pi), fv = fsig(pf), gv = ftanh(pg), ov = fsig(po);
            creg = fv * creg + iv * gv;
            hreg = ov * ftanh(creg);
            hl[tid] = hreg;
            if (MODE == 1) outp[t * 256 + tid] = hreg;
        }
        __syncthreads();
    }
}

// self-attention (512-thread variant), 4 time steps per iteration
DI void selfatt_body(const float* __restrict__ x, const float* __restrict__ Wg,
                     const float* __restrict__ bg, const float* __restrict__ Wa,
                     const float* __restrict__ ba, float* __restrict__ sa,
                     int b, float* s)
{
    float* xl  = s;                // 128*33
    float* Wgl = s + 4224;
    float* WaT = s + 8448;
    float* bgl = s + 12672;        // 128
    float* bal = s + 12800;        // 32
    float* gl  = s + 12832;        // 4*128
    float* pp  = s + 13344;        // 4*4*32

    const int tid = threadIdx.x;
    for (int i = tid; i < 4096; i += 512) {
        int r = i >> 5, n = i & 31;
        xl[r * 33 + n]  = x[b * 4096 + i];
        Wgl[r * 33 + n] = Wg[i];
        WaT[(i & 127) * 33 + (i >> 7)] = Wa[i];
    }
    if (tid < 128) bgl[tid] = bg[tid];
    else if (tid < 160) bal[tid - 128] = ba[tid - 128];
    __syncthreads();

    const int tl = tid >> 7;          // 0..3
    for (int it = 0; it < 32; ++it) {
        {   const int m = tid & 127;
            const int t = it * 4 + tl;
            float acc = bgl[m];
            #pragma unroll
            for (int n = 0; n < 32; ++n) acc += xl[t * 33 + n] * Wgl[m * 33 + n];
            gl[tl * 128 + m] = ftanh(acc);
        }
        __syncthreads();
        {   const int n = tid & 31, c = (tid >> 5) & 3;
            float acc = 0.f;
            #pragma unroll
            for (int j = 0; j < 32; ++j) {
                int m = c * 32 + j;
                acc += gl[tl * 128 + m] * WaT[m * 33 + n];
            }
            pp[(tl * 4 + c) * 32 + n] = acc;
        }
        __syncthreads();
        if (tid < 128) {
            const int tl2 = tid >> 5, n = tid & 31;
            const int t = it * 4 + tl2;
            float sv = pp[(tl2 * 4 + 0) * 32 + n] + pp[(tl2 * 4 + 1) * 32 + n]
                     + pp[(tl2 * 4 + 2) * 32 + n] + pp[(tl2 * 4 + 3) * 32 + n] + bal[n];
            sa[b * 4096 + t * 32 + n] = fsig(sv) * xl[t * 33 + n];
        }
        __syncthreads();
    }
}

// k1: blocks 0..127 -> LSTM0 (record rec); blocks 128..255 -> self-attention (sa)
__global__ __launch_bounds__(512, 2)
void k1_lstm0_sa(const float* __restrict__ x,
                 const float* __restrict__ Wih0, const float* __restrict__ Whh0,
                 const float* __restrict__ bih0, const float* __restrict__ bhh0,
                 const float* __restrict__ Wg, const float* __restrict__ bg,
                 const float* __restrict__ Wa, const float* __restrict__ ba,
                 float* __restrict__ rec, float* __restrict__ sa)
{
    __shared__ float smem[13856];
    const int blk = blockIdx.x;
    if (blk < 128) {
        lstm_scan2<0>(x + blk * 4096, Wih0, Whh0, bih0, bhh0,
                      rec + blk * 32768, nullptr, smem);
    } else {
        selfatt_body(x, Wg, bg, Wa, ba, sa, blk - 128, smem);
    }
}

// k3: blocks 0..127 -> LSTM1 (ia -> out cols 0..127); 128..255 -> LSTM2 (sa -> cols 128..255)
__global__ __launch_bounds__(512, 2)
void k3_lstm12(const float* __restrict__ ia, const float* __restrict__ sa,
               const float* __restrict__ Wih1, const float* __restrict__ Whh1,
               const float* __restrict__ bih1, const float* __restrict__ bhh1,
               const float* __restrict__ Wih2, const float* __restrict__ Whh2,
               const float* __restrict__ bih2, const float* __restrict__ bhh2,
               float* __restrict__ out)
{
    __shared__ float smem[6272];
    const int blk = blockIdx.x;
    if (blk < 128) {
        lstm_scan2<1>(ia + blk * 4096, Wih1, Whh1, bih1, bhh1,
                      nullptr, out + blk * 32768, smem);
    } else {
        const int b = blk - 128;
        lstm_scan2<1>(sa + b * 4096, Wih2, Whh2, bih2, bhh2,
                      nullptr, out + b * 32768 + 128, smem);
    }
}

// ===================== kB: input attention =====================
// block = (b, 32-t chunk); 512 threads: ta = tid>>2 (tau / m-row), q = tid&3.
// uxr/ver2 pinned in VGPRs via asm (blocks rematerialization); wl precomputed per chunk.
__global__ __launch_bounds__(512, 4)
void kB_attn(const float* __restrict__ x,    // [128][128][32]
             const float* __restrict__ Ue,   // [128][32]
             const float* __restrict__ We,   // [128][256]
             const float* __restrict__ Ve,   // [128]
             const float* __restrict__ rec,  // [B][T][256] pre-step (h|c)
             float* __restrict__ ia)         // [128][128][32]
{
    __shared__ float xl[4608];     // [tau][36] padded
    __shared__ float wl[4608];     // [32 t][4 q][36] padded, pre-scaled by 2
    __shared__ float ubuf[4608];   // union: hsp [16][272] then Uel [128][36]
    __shared__ float ev[128];
    __shared__ float av[128];
    __shared__ float iap[576];     // [16][36]
    __shared__ float wred[2];
    __shared__ float wsum[2];

    const int tid = threadIdx.x;
    const int b  = blockIdx.x >> 2;
    const int tc = blockIdx.x & 3;
    const int ta = tid >> 2;       // 0..127
    const int q  = tid & 3;

    // We row ta, k-quarter q -> registers (flat offset = tid*64, fully coalesced)
    float4 wer[16];
    {
        const float4* p = (const float4*)(We + tid * 64);
        #pragma unroll
        for (int i = 0; i < 16; ++i) wer[i] = p[i];
    }
    for (int i = tid; i < 4096; i += 512)
        xl[(i >> 5) * 36 + (i & 31)] = x[b * 4096 + i];

    // ---- build wl[t][.] = 2 * (We @ [h;c])(t) for the 32 t of this chunk, 16 t per half ----
    const long rbase = (long)b * 32768 + (long)tc * 32 * 256;
    for (int h2 = 0; h2 < 2; ++h2) {
        __syncthreads();
        #pragma unroll
        for (int s = 0; s < 8; ++s) {
            int f = tid + 512 * s;             // 0..4095
            int tl = f >> 8, k = f & 255;
            ubuf[tl * 272 + (k >> 6) * 68 + (k & 63)] =
                rec[rbase + (h2 * 16 + tl) * 256 + k];
        }
        __syncthreads();
        for (int tl = 0; tl < 16; ++tl) {
            const float4* hp = (const float4*)(ubuf + tl * 272 + q * 68);
            float acc = 0.f;
            #pragma unroll
            for (int i = 0; i < 16; ++i) {
                float4 v = hp[i];
                acc += wer[i].x * v.x + wer[i].y * v.y + wer[i].z * v.z + wer[i].w * v.w;
            }
            acc += __shfl_xor(acc, 1);
            acc += __shfl_xor(acc, 2);
            if (q == 0)
                wl[(h2 * 16 + tl) * 144 + (ta & 3) * 36 + (ta >> 2)] = 2.0f * acc;
        }
    }
    __syncthreads();

    // ---- Uel into ubuf, then uxr[j] = 2 * sum_n x[ta][n]*Ue[4j+q][n] ----
    for (int i = tid; i < 4096; i += 512)
        ubuf[(i >> 5) * 36 + (i & 31)] = Ue[i];
    __syncthreads();

    float uxr[32];
    {
        float xr[32];
        const float4* xp = (const float4*)(xl + ta * 36);
        #pragma unroll
        for (int i = 0; i < 8; ++i) {
            float4 v = xp[i];
            xr[4*i] = v.x; xr[4*i+1] = v.y; xr[4*i+2] = v.z; xr[4*i+3] = v.w;
        }
        #pragma unroll
        for (int j = 0; j < 32; ++j) {
            const float4* up = (const float4*)(ubuf + (4 * j + q) * 36);
            float acc = 0.f;
            #pragma unroll
            for (int i = 0; i < 8; ++i) {
                float4 v = up[i];
                acc += xr[4*i] * v.x + xr[4*i+1] * v.y + xr[4*i+2] * v.z + xr[4*i+3] * v.w;
            }
            uxr[j] = 2.0f * acc;
        }
    }

    float ver2[32];
    #pragma unroll
    for (int j = 0; j < 32; ++j) ver2[j] = 2.0f * Ve[4 * j + q];
    float VeTot;
    {
        float vs = 0.f;
        #pragma unroll
        for (int j = 0; j < 32; ++j) vs += ver2[j];
        vs += __shfl_xor(vs, 1);
        vs += __shfl_xor(vs, 2);
        VeTot = 0.5f * vs;
    }
    // pin uxr/ver2 into VGPRs: asm outputs cannot be rematerialized by the scheduler
    #pragma unroll
    for (int j = 0; j < 32; ++j) {
        asm volatile("" : "+v"(uxr[j]));
        asm volatile("" : "+v"(ver2[j]));
    }

    // ---- main loop over the 32 t of this chunk ----
    for (int tl = 0; tl < 32; ++tl) {
        const int t = tc * 32 + tl;
        // e = VeTot - sum_m ver2[m] / (exp(2z)+1);  uxr/wl hold the two halves of 2z
        float acc2 = 0.f;
        const float4* wr = (const float4*)(wl + tl * 144 + q * 36);
        #pragma unroll
        for (int j4 = 0; j4 < 8; ++j4) {
            float4 w4 = wr[j4];
            {   float zs = uxr[4*j4+0] + w4.x;
                acc2 += ver2[4*j4+0] * __frcp_rn(__expf(zs) + 1.0f); }
            {   float zs = uxr[4*j4+1] + w4.y;
                acc2 += ver2[4*j4+1] * __frcp_rn(__expf(zs) + 1.0f); }
            {   float zs = uxr[4*j4+2] + w4.z;
                acc2 += ver2[4*j4+2] * __frcp_rn(__expf(zs) + 1.0f); }
            {   float zs = uxr[4*j4+3] + w4.w;
                acc2 += ver2[4*j4+3] * __frcp_rn(__expf(zs) + 1.0f); }
        }
        acc2 += __shfl_xor(acc2, 1);
        acc2 += __shfl_xor(acc2, 2);
        if (q == 0) ev[ta] = VeTot - acc2;
        __syncthreads();                       // B1

        float vv = 0.f, aa;
        if (tid < 128) {
            vv = ev[tid];
            float m2 = vv;
            #pragma unroll
            for (int o = 32; o > 0; o >>= 1) m2 = fmaxf(m2, __shfl_xor(m2, o));
            if ((tid & 63) == 0) wred[tid >> 6] = m2;
        }
        __syncthreads();                       // B2
        if (tid < 128) {
            float M = fmaxf(wred[0], wred[1]);
            aa = __expf(vv - M);
            av[tid] = aa;
            float s = aa;
            #pragma unroll
            for (int o = 32; o > 0; o >>= 1) s += __shfl_xor(s, o);
            if ((tid & 63) == 0) wsum[tid >> 6] = s;
        }
        __syncthreads();                       // B3
        {   const int n = tid & 31, g = tid >> 5;
            float accp = 0.f;
            #pragma unroll
            for (int jj = 0; jj < 8; ++jj) {
                const int t2 = g * 8 + jj;
                accp += av[t2] * xl[t2 * 36 + n];
            }
            iap[g * 36 + n] = accp;
        }
        __syncthreads();                       // B4
        if (tid < 32) {
            float s = 0.f;
            #pragma unroll
            for (int g = 0; g < 16; ++g) s += iap[g * 36 + tid];
            float scale = __fdividef(1.0f, wsum[0] + wsum[1]);
            ia[((long)b * 128 + t) * 32 + tid] = s * scale;
        }
    }
}

extern "C" void kernel_launch(void* const* d_in, const int* in_sizes, int n_in,
                              void* d_out, int out_size, void* d_ws, size_t ws_size,
                              hipStream_t stream)
{
    const float* x    = (const float*)d_in[0];
    const float* Wih0 = (const float*)d_in[1];
    const float* Whh0 = (const float*)d_in[2];
    const float* bih0 = (const float*)d_in[3];
    const float* bhh0 = (const float*)d_in[4];
    const float* We   = (const float*)d_in[5];
    const float* Ue   = (const float*)d_in[6];
    const float* Ve   = (const float*)d_in[7];
    const float* Wg   = (const float*)d_in[8];
    const float* bg   = (const float*)d_in[9];
    const float* Wa   = (const float*)d_in[10];
    const float* ba   = (const float*)d_in[11];
    const float* Wih1 = (const float*)d_in[12];
    const float* Whh1 = (const float*)d_in[13];
    const float* bih1 = (const float*)d_in[14];
    const float* bhh1 = (const float*)d_in[15];
    const float* Wih2 = (const float*)d_in[16];
    const float* Whh2 = (const float*)d_in[17];
    const float* bih2 = (const float*)d_in[18];
    const float* bhh2 = (const float*)d_in[19];

    float* out = (float*)d_out;
    float* ws  = (float*)d_ws;
    // workspace (floats): sa 524288 | rec 4194304 | ia 524288
    float* sa  = ws;
    float* rec = ws + 524288;
    float* iaw = ws + 4718592;

    k1_lstm0_sa<<<256, 512, 0, stream>>>(x, Wih0, Whh0, bih0, bhh0,
                                         Wg, bg, Wa, ba, rec, sa);
    kB_attn<<<512, 512, 0, stream>>>(x, Ue, We, Ve, rec, iaw);
    k3_lstm12<<<256, 512, 0, stream>>>(iaw, sa, Wih1, Whh1, bih1, bhh1,
                                       Wih2, Whh2, bih2, bhh2, out);
}

// Round 5
// 553.381 us; speedup vs baseline: 1.0271x; 1.0271x over previous
//
#include <hip/hip_runtime.h>

#define DI __device__ __forceinline__

DI float fsig(float v)  { return 1.0f / (1.0f + __expf(-v)); }
DI float ftanh(float v) { return 1.0f - 2.0f / (__expf(2.0f * v) + 1.0f); }

// ===================== LSTM scan, 4-way K-split =====================
// 512 threads: r0 = tid&127 (hidden unit), kq = tid>>7 (K-quarter of [x(32)|h(128)]).
// Thread computes partials for all 4 gates of unit r0 over its 40-float K-quarter.
// Weights: 4 gates x 10 float4 = 160 VGPRs — needs the full 256-VGPR budget, so the
// enclosing kernels must NOT declare a min-waves launch bound (r4 lesson: (512,2)
// capped VGPRs at 128 and spilled the weights to scratch).
template <int MODE>
DI void lstm_scan2(const float* __restrict__ xin,  // [128][32]
                   const float* __restrict__ Wih,  // [512][32]
                   const float* __restrict__ Whh,  // [512][128]
                   const float* __restrict__ bih,
                   const float* __restrict__ bhh,
                   float* __restrict__ rec,        // MODE 0: [128][256]
                   float* __restrict__ outp,       // MODE 1: stride 256
                   float* lds)
{
    const int tid = threadIdx.x;
    const int r0 = tid & 127;
    const int kq = tid >> 7;
    float* xl = lds;          // 4096
    float* hl = lds + 4096;   // 128
    float* pl = lds + 4224;   // 2048 : pl[kq*512 + g*128 + r0]

    for (int i = tid; i < 4096; i += 512) xl[i] = xin[i];
    if (tid < 128) hl[tid] = 0.f;

    // K-quarter kq covers virtual K index [40kq, 40kq+40):
    //  kq0: Wih[r][0..32) + Whh[r][0..8);  kq>=1: Whh[r][40kq-32 .. 40kq+8)
    float4 wq[4][10];
    if (kq == 0) {
        #pragma unroll
        for (int g = 0; g < 4; ++g) {
            const int r = g * 128 + r0;
            const float4* pi4 = (const float4*)(Wih + r * 32);
            #pragma unroll
            for (int i = 0; i < 8; ++i) wq[g][i] = pi4[i];
            const float4* ph4 = (const float4*)(Whh + r * 128);
            wq[g][8] = ph4[0]; wq[g][9] = ph4[1];
        }
    } else {
        const int off = 40 * kq - 32;  // 8, 48, 88
        #pragma unroll
        for (int g = 0; g < 4; ++g) {
            const int r = g * 128 + r0;
            const float4* ph4 = (const float4*)(Whh + r * 128 + off);
            #pragma unroll
            for (int j = 0; j < 10; ++j) wq[g][j] = ph4[j];
        }
    }
    float b0 = 0.f, b1 = 0.f, b2 = 0.f, b3 = 0.f, hreg = 0.f, creg = 0.f;
    if (tid < 128) {
        b0 = bih[tid]       + bhh[tid];
        b1 = bih[128 + tid] + bhh[128 + tid];
        b2 = bih[256 + tid] + bhh[256 + tid];
        b3 = bih[384 + tid] + bhh[384 + tid];
    }
    __syncthreads();

    for (int t = 0; t < 128; ++t) {
        float a0 = 0.f, a1 = 0.f, a2 = 0.f, a3 = 0.f;
        if (kq == 0) {
            const float4* x4 = (const float4*)(xl + t * 32);
            #pragma unroll
            for (int i = 0; i < 8; ++i) {
                float4 v = x4[i];
                a0 += wq[0][i].x * v.x + wq[0][i].y * v.y + wq[0][i].z * v.z + wq[0][i].w * v.w;
                a1 += wq[1][i].x * v.x + wq[1][i].y * v.y + wq[1][i].z * v.z + wq[1][i].w * v.w;
                a2 += wq[2][i].x * v.x + wq[2][i].y * v.y + wq[2][i].z * v.z + wq[2][i].w * v.w;
                a3 += wq[3][i].x * v.x + wq[3][i].y * v.y + wq[3][i].z * v.z + wq[3][i].w * v.w;
            }
            const float4* h4 = (const float4*)hl;
            #pragma unroll
            for (int j = 0; j < 2; ++j) {
                float4 v = h4[j];
                a0 += wq[0][8+j].x * v.x + wq[0][8+j].y * v.y + wq[0][8+j].z * v.z + wq[0][8+j].w * v.w;
                a1 += wq[1][8+j].x * v.x + wq[1][8+j].y * v.y + wq[1][8+j].z * v.z + wq[1][8+j].w * v.w;
                a2 += wq[2][8+j].x * v.x + wq[2][8+j].y * v.y + wq[2][8+j].z * v.z + wq[2][8+j].w * v.w;
                a3 += wq[3][8+j].x * v.x + wq[3][8+j].y * v.y + wq[3][8+j].z * v.z + wq[3][8+j].w * v.w;
            }
        } else {
            const float4* h4 = (const float4*)(hl + 40 * kq - 32);
            #pragma unroll
            for (int j = 0; j < 10; ++j) {
                float4 v = h4[j];
                a0 += wq[0][j].x * v.x + wq[0][j].y * v.y + wq[0][j].z * v.z + wq[0][j].w * v.w;
                a1 += wq[1][j].x * v.x + wq[1][j].y * v.y + wq[1][j].z * v.z + wq[1][j].w * v.w;
                a2 += wq[2][j].x * v.x + wq[2][j].y * v.y + wq[2][j].z * v.z + wq[2][j].w * v.w;
                a3 += wq[3][j].x * v.x + wq[3][j].y * v.y + wq[3][j].z * v.z + wq[3][j].w * v.w;
            }
        }
        pl[kq * 512 +       r0] = a0;
        pl[kq * 512 + 128 + r0] = a1;
        pl[kq * 512 + 256 + r0] = a2;
        pl[kq * 512 + 384 + r0] = a3;
        __syncthreads();
        if (tid < 128) {
            float pi = b0 + pl[tid]        + pl[512 + tid]  + pl[1024 + tid] + pl[1536 + tid];
            float pf = b1 + pl[128 + tid]  + pl[640 + tid]  + pl[1152 + tid] + pl[1664 + tid];
            float pg = b2 + pl[256 + tid]  + pl[768 + tid]  + pl[1280 + tid] + pl[1792 + tid];
            float po = b3 + pl[384 + tid]  + pl[896 + tid]  + pl[1408 + tid] + pl[1920 + tid];
            if (MODE == 0) {
                rec[t * 256 + tid]       = hreg;   // pre-step state
                rec[t * 256 + 128 + tid] = creg;
            }
            float iv = fsig(pi), fv = fsig(pf), gv = ftanh(pg), ov = fsig(po);
            creg = fv * creg + iv * gv;
            hreg = ov * ftanh(creg);
            hl[tid] = hreg;
            if (MODE == 1) outp[t * 256 + tid] = hreg;
        }
        __syncthreads();
    }
}

// self-attention (512-thread variant), 4 time steps per iteration
DI void selfatt_body(const float* __restrict__ x, const float* __restrict__ Wg,
                     const float* __restrict__ bg, const float* __restrict__ Wa,
                     const float* __restrict__ ba, float* __restrict__ sa,
                     int b, float* s)
{
    float* xl  = s;                // 128*33
    float* Wgl = s + 4224;
    float* WaT = s + 8448;
    float* bgl = s + 12672;        // 128
    float* bal = s + 12800;        // 32
    float* gl  = s + 12832;        // 4*128
    float* pp  = s + 13344;        // 4*4*32

    const int tid = threadIdx.x;
    for (int i = tid; i < 4096; i += 512) {
        int r = i >> 5, n = i & 31;
        xl[r * 33 + n]  = x[b * 4096 + i];
        Wgl[r * 33 + n] = Wg[i];
        WaT[(i & 127) * 33 + (i >> 7)] = Wa[i];
    }
    if (tid < 128) bgl[tid] = bg[tid];
    else if (tid < 160) bal[tid - 128] = ba[tid - 128];
    __syncthreads();

    const int tl = tid >> 7;          // 0..3
    for (int it = 0; it < 32; ++it) {
        {   const int m = tid & 127;
            const int t = it * 4 + tl;
            float acc = bgl[m];
            #pragma unroll
            for (int n = 0; n < 32; ++n) acc += xl[t * 33 + n] * Wgl[m * 33 + n];
            gl[tl * 128 + m] = ftanh(acc);
        }
        __syncthreads();
        {   const int n = tid & 31, c = (tid >> 5) & 3;
            float acc = 0.f;
            #pragma unroll
            for (int j = 0; j < 32; ++j) {
                int m = c * 32 + j;
                acc += gl[tl * 128 + m] * WaT[m * 33 + n];
            }
            pp[(tl * 4 + c) * 32 + n] = acc;
        }
        __syncthreads();
        if (tid < 128) {
            const int tl2 = tid >> 5, n = tid & 31;
            const int t = it * 4 + tl2;
            float sv = pp[(tl2 * 4 + 0) * 32 + n] + pp[(tl2 * 4 + 1) * 32 + n]
                     + pp[(tl2 * 4 + 2) * 32 + n] + pp[(tl2 * 4 + 3) * 32 + n] + bal[n];
            sa[b * 4096 + t * 32 + n] = fsig(sv) * xl[t * 33 + n];
        }
        __syncthreads();
    }
}

// k1: blocks 0..127 -> LSTM0 (record rec); blocks 128..255 -> self-attention (sa)
// NOTE: no min-waves bound — lstm_scan2 needs ~200 VGPRs (160 weights + temps).
__global__ __launch_bounds__(512)
void k1_lstm0_sa(const float* __restrict__ x,
                 const float* __restrict__ Wih0, const float* __restrict__ Whh0,
                 const float* __restrict__ bih0, const float* __restrict__ bhh0,
                 const float* __restrict__ Wg, const float* __restrict__ bg,
                 const float* __restrict__ Wa, const float* __restrict__ ba,
                 float* __restrict__ rec, float* __restrict__ sa)
{
    __shared__ float smem[13856];
    const int blk = blockIdx.x;
    if (blk < 128) {
        lstm_scan2<0>(x + blk * 4096, Wih0, Whh0, bih0, bhh0,
                      rec + blk * 32768, nullptr, smem);
    } else {
        selfatt_body(x, Wg, bg, Wa, ba, sa, blk - 128, smem);
    }
}

// k3: blocks 0..127 -> LSTM1 (ia -> out cols 0..127); 128..255 -> LSTM2 (sa -> cols 128..255)
__global__ __launch_bounds__(512)
void k3_lstm12(const float* __restrict__ ia, const float* __restrict__ sa,
               const float* __restrict__ Wih1, const float* __restrict__ Whh1,
               const float* __restrict__ bih1, const float* __restrict__ bhh1,
               const float* __restrict__ Wih2, const float* __restrict__ Whh2,
               const float* __restrict__ bih2, const float* __restrict__ bhh2,
               float* __restrict__ out)
{
    __shared__ float smem[6272];
    const int blk = blockIdx.x;
    if (blk < 128) {
        lstm_scan2<1>(ia + blk * 4096, Wih1, Whh1, bih1, bhh1,
                      nullptr, out + blk * 32768, smem);
    } else {
        const int b = blk - 128;
        lstm_scan2<1>(sa + b * 4096, Wih2, Whh2, bih2, bhh2,
                      nullptr, out + b * 32768 + 128, smem);
    }
}

// ===================== kB: input attention =====================
// block = (b, 32-t chunk); 512 threads: ta = tid>>2 (tau / m-row), q = tid&3.
// uxr/ver2 pinned in VGPRs via asm; wl precomputed per chunk.
// Main loop batches 4 time steps per softmax round: all 512 threads active in
// softmax/weighted-sum phases (tt = tid>>7 owns one t), 5 barriers per 4 t.
__global__ __launch_bounds__(512, 4)
void kB_attn(const float* __restrict__ x,    // [128][128][32]
             const float* __restrict__ Ue,   // [128][32]
             const float* __restrict__ We,   // [128][256]
             const float* __restrict__ Ve,   // [128]
             const float* __restrict__ rec,  // [B][T][256] pre-step (h|c)
             float* __restrict__ ia)         // [128][128][32]
{
    __shared__ float xl[4608];     // [tau][36] padded
    __shared__ float wl[4608];     // [32 t][4 q][36] padded, pre-scaled by 2
    __shared__ float ubuf[4608];   // union: hsp [16][272] then Uel [128][36]
    __shared__ float ev[512];      // [tt][128]
    __shared__ float av[512];      // [tt][128]
    __shared__ float iap[576];     // [tt][4 g][36]
    __shared__ float wred[8];      // [tt][2]
    __shared__ float wsum[8];      // [tt][2]

    const int tid = threadIdx.x;
    const int b  = blockIdx.x >> 2;
    const int tc = blockIdx.x & 3;
    const int ta = tid >> 2;       // 0..127
    const int q  = tid & 3;

    // We row ta, k-quarter q -> registers (flat offset = tid*64, fully coalesced)
    float4 wer[16];
    {
        const float4* p = (const float4*)(We + tid * 64);
        #pragma unroll
        for (int i = 0; i < 16; ++i) wer[i] = p[i];
    }
    for (int i = tid; i < 4096; i += 512)
        xl[(i >> 5) * 36 + (i & 31)] = x[b * 4096 + i];

    // ---- build wl[t][.] = 2 * (We @ [h;c])(t) for the 32 t of this chunk, 16 t per half ----
    const long rbase = (long)b * 32768 + (long)tc * 32 * 256;
    for (int h2 = 0; h2 < 2; ++h2) {
        __syncthreads();
        #pragma unroll
        for (int s = 0; s < 8; ++s) {
            int f = tid + 512 * s;             // 0..4095
            int tl = f >> 8, k = f & 255;
            ubuf[tl * 272 + (k >> 6) * 68 + (k & 63)] =
                rec[rbase + (h2 * 16 + tl) * 256 + k];
        }
        __syncthreads();
        for (int tl = 0; tl < 16; ++tl) {
            const float4* hp = (const float4*)(ubuf + tl * 272 + q * 68);
            float acc = 0.f;
            #pragma unroll
            for (int i = 0; i < 16; ++i) {
                float4 v = hp[i];
                acc += wer[i].x * v.x + wer[i].y * v.y + wer[i].z * v.z + wer[i].w * v.w;
            }
            acc += __shfl_xor(acc, 1);
            acc += __shfl_xor(acc, 2);
            if (q == 0)
                wl[(h2 * 16 + tl) * 144 + (ta & 3) * 36 + (ta >> 2)] = 2.0f * acc;
        }
    }
    __syncthreads();

    // ---- Uel into ubuf, then uxr[j] = 2 * sum_n x[ta][n]*Ue[4j+q][n] ----
    for (int i = tid; i < 4096; i += 512)
        ubuf[(i >> 5) * 36 + (i & 31)] = Ue[i];
    __syncthreads();

    float uxr[32];
    {
        float xr[32];
        const float4* xp = (const float4*)(xl + ta * 36);
        #pragma unroll
        for (int i = 0; i < 8; ++i) {
            float4 v = xp[i];
            xr[4*i] = v.x; xr[4*i+1] = v.y; xr[4*i+2] = v.z; xr[4*i+3] = v.w;
        }
        #pragma unroll
        for (int j = 0; j < 32; ++j) {
            const float4* up = (const float4*)(ubuf + (4 * j + q) * 36);
            float acc = 0.f;
            #pragma unroll
            for (int i = 0; i < 8; ++i) {
                float4 v = up[i];
                acc += xr[4*i] * v.x + xr[4*i+1] * v.y + xr[4*i+2] * v.z + xr[4*i+3] * v.w;
            }
            uxr[j] = 2.0f * acc;
        }
    }

    float ver2[32];
    #pragma unroll
    for (int j = 0; j < 32; ++j) ver2[j] = 2.0f * Ve[4 * j + q];
    float VeTot;
    {
        float vs = 0.f;
        #pragma unroll
        for (int j = 0; j < 32; ++j) vs += ver2[j];
        vs += __shfl_xor(vs, 1);
        vs += __shfl_xor(vs, 2);
        VeTot = 0.5f * vs;
    }
    // pin uxr/ver2 into VGPRs: asm outputs cannot be rematerialized by the scheduler
    #pragma unroll
    for (int j = 0; j < 32; ++j) {
        asm volatile("" : "+v"(uxr[j]));
        asm volatile("" : "+v"(ver2[j]));
    }

    // ---- main loop: 8 iterations x 4 time steps ----
    for (int it = 0; it < 8; ++it) {
        // E: e-partials for 4 t's.  e = VeTot - sum_m ver2[m] / (exp(2z)+1)
        float a20 = 0.f, a21 = 0.f, a22 = 0.f, a23 = 0.f;
        const float4* wr0 = (const float4*)(wl + (it * 4 + 0) * 144 + q * 36);
        const float4* wr1 = (const float4*)(wl + (it * 4 + 1) * 144 + q * 36);
        const float4* wr2 = (const float4*)(wl + (it * 4 + 2) * 144 + q * 36);
        const float4* wr3 = (const float4*)(wl + (it * 4 + 3) * 144 + q * 36);
        #pragma unroll
        for (int j4 = 0; j4 < 8; ++j4) {
            const float u0 = uxr[4*j4+0], u1 = uxr[4*j4+1], u2 = uxr[4*j4+2], u3 = uxr[4*j4+3];
            const float v0 = ver2[4*j4+0], v1 = ver2[4*j4+1], v2 = ver2[4*j4+2], v3 = ver2[4*j4+3];
            {   float4 w = wr0[j4];
                a20 += v0 * __frcp_rn(__expf(u0 + w.x) + 1.0f)
                     + v1 * __frcp_rn(__expf(u1 + w.y) + 1.0f)
                     + v2 * __frcp_rn(__expf(u2 + w.z) + 1.0f)
                     + v3 * __frcp_rn(__expf(u3 + w.w) + 1.0f); }
            {   float4 w = wr1[j4];
                a21 += v0 * __frcp_rn(__expf(u0 + w.x) + 1.0f)
                     + v1 * __frcp_rn(__expf(u1 + w.y) + 1.0f)
                     + v2 * __frcp_rn(__expf(u2 + w.z) + 1.0f)
                     + v3 * __frcp_rn(__expf(u3 + w.w) + 1.0f); }
            {   float4 w = wr2[j4];
                a22 += v0 * __frcp_rn(__expf(u0 + w.x) + 1.0f)
                     + v1 * __frcp_rn(__expf(u1 + w.y) + 1.0f)
                     + v2 * __frcp_rn(__expf(u2 + w.z) + 1.0f)
                     + v3 * __frcp_rn(__expf(u3 + w.w) + 1.0f); }
            {   float4 w = wr3[j4];
                a23 += v0 * __frcp_rn(__expf(u0 + w.x) + 1.0f)
                     + v1 * __frcp_rn(__expf(u1 + w.y) + 1.0f)
                     + v2 * __frcp_rn(__expf(u2 + w.z) + 1.0f)
                     + v3 * __frcp_rn(__expf(u3 + w.w) + 1.0f); }
        }
        a20 += __shfl_xor(a20, 1); a20 += __shfl_xor(a20, 2);
        a21 += __shfl_xor(a21, 1); a21 += __shfl_xor(a21, 2);
        a22 += __shfl_xor(a22, 1); a22 += __shfl_xor(a22, 2);
        a23 += __shfl_xor(a23, 1); a23 += __shfl_xor(a23, 2);
        if (q == 0) {
            ev[      ta] = VeTot - a20;
            ev[128 + ta] = VeTot - a21;
            ev[256 + ta] = VeTot - a22;
            ev[384 + ta] = VeTot - a23;
        }
        __syncthreads();                       // B1

        // S: softmax over 128 taus, one t per 128-thread group
        const int tt = tid >> 7, r = tid & 127;
        const float vv = ev[tt * 128 + r];
        {
            float m2 = vv;
            #pragma unroll
            for (int o = 32; o > 0; o >>= 1) m2 = fmaxf(m2, __shfl_xor(m2, o));
            if ((tid & 63) == 0) wred[tid >> 6] = m2;
        }
        __syncthreads();                       // B2
        {
            const float M = fmaxf(wred[tt * 2], wred[tt * 2 + 1]);
            const float aa = __expf(vv - M);
            av[tt * 128 + r] = aa;
            float s = aa;
            #pragma unroll
            for (int o = 32; o > 0; o >>= 1) s += __shfl_xor(s, o);
            if ((tid & 63) == 0) wsum[tid >> 6] = s;
        }
        __syncthreads();                       // B3

        // W: weighted sum over taus (4 tau-groups x 32 n per t)
        {
            const int g = (tid >> 5) & 3, n = tid & 31;
            float accp = 0.f;
            #pragma unroll
            for (int j = 0; j < 32; ++j) {
                const int t2 = g * 32 + j;
                accp += av[tt * 128 + t2] * xl[t2 * 36 + n];
            }
            iap[tt * 144 + g * 36 + n] = accp;
        }
        __syncthreads();                       // B4

        // F: finalize 4 t's with 128 threads
        if (tid < 128) {
            const int tf = tid >> 5, n = tid & 31;
            const float s2 = iap[tf * 144 +      n] + iap[tf * 144 + 36 + n]
                           + iap[tf * 144 + 72 + n] + iap[tf * 144 + 108 + n];
            const float scale = __fdividef(1.0f, wsum[tf * 2] + wsum[tf * 2 + 1]);
            ia[((long)b * 128 + tc * 32 + it * 4 + tf) * 32 + n] = s2 * scale;
        }
        __syncthreads();                       // B5
    }
}

extern "C" void kernel_launch(void* const* d_in, const int* in_sizes, int n_in,
                              void* d_out, int out_size, void* d_ws, size_t ws_size,
                              hipStream_t stream)
{
    const float* x    = (const float*)d_in[0];
    const float* Wih0 = (const float*)d_in[1];
    const float* Whh0 = (const float*)d_in[2];
    const float* bih0 = (const float*)d_in[3];
    const float* bhh0 = (const float*)d_in[4];
    const float* We   = (const float*)d_in[5];
    const float* Ue   = (const float*)d_in[6];
    const float* Ve   = (const float*)d_in[7];
    const float* Wg   = (const float*)d_in[8];
    const float* bg   = (const float*)d_in[9];
    const float* Wa   = (const float*)d_in[10];
    const float* ba   = (const float*)d_in[11];
    const float* Wih1 = (const float*)d_in[12];
    const float* Whh1 = (const float*)d_in[13];
    const float* bih1 = (const float*)d_in[14];
    const float* bhh1 = (const float*)d_in[15];
    const float* Wih2 = (const float*)d_in[16];
    const float* Whh2 = (const float*)d_in[17];
    const float* bih2 = (const float*)d_in[18];
    const float* bhh2 = (const float*)d_in[19];

    float* out = (float*)d_out;
    float* ws  = (float*)d_ws;
    // workspace (floats): sa 524288 | rec 4194304 | ia 524288
    float* sa  = ws;
    float* rec = ws + 524288;
    float* iaw = ws + 4718592;

    k1_lstm0_sa<<<256, 512, 0, stream>>>(x, Wih0, Whh0, bih0, bhh0,
                                         Wg, bg, Wa, ba, rec, sa);
    kB_attn<<<512, 512, 0, stream>>>(x, Ue, We, Ve, rec, iaw);
    k3_lstm12<<<256, 512, 0, stream>>>(iaw, sa, Wih1, Whh1, bih1, bhh1,
                                       Wih2, Whh2, bih2, bhh2, out);
}